// Round 9
// baseline (861.329 us; speedup 1.0000x reference)
//
#include <hip/hip_runtime.h>
#include <math.h>

#define BKS 60      // B*K sequences
#define TL  1000    // T
#define NF  128     // N features
#define SD  12      // state dim S
#define RD  8       // dt rank
#define NCH 32      // scan chunks
#define CLEN 32     // chunk length
#define NTOK (BKS*TL)
#define MT  64      // GEMM token tile
#define NBLK ((NTOK + MT - 1)/MT)   // 938
#define LNP 129     // cross_ln LDS stride
// bf16 weight pool: in_w 131072 | out_w 65536 | cb_w 16384 | xp_w 16384
#define OFF_OW  131072
#define OFF_CBW 196608
#define OFF_XW  212992
#define WCNT    229376

typedef __bf16 bf16x8 __attribute__((ext_vector_type(8)));
typedef float  f32x4  __attribute__((ext_vector_type(4)));

__device__ __forceinline__ float siluf(float x){ return x / (1.f + __expf(-x)); }
__device__ __forceinline__ float softplusf(float x){
  if (x > 20.f) return x;
  float e = __expf(x);
  return (x < -20.f) ? e : __logf(1.f + e);
}
__device__ __forceinline__ ushort bf16r(float f){          // RNE fp32->bf16
  uint u = __float_as_uint(f);
  return (ushort)((u + 0x7FFFu + ((u>>16)&1u)) >> 16);
}
__device__ __forceinline__ float bf2f(ushort h){ return __uint_as_float(((uint)h)<<16); }

// ---- K0: x (B,N,T,K) -> seq (B*K, T, N)
__global__ __launch_bounds__(256) void k_ingest(const float* __restrict__ x, float* __restrict__ seq){
  const int b = blockIdx.x / TL, t = blockIdx.x % TL;
  __shared__ float tile[30*NF];
  for (int e = threadIdx.x; e < 30*NF; e += 256){
    int n = e / 30, k = e - n*30;
    tile[k*NF + n] = x[((size_t)(b*NF + n)*TL + t)*30 + k];
  }
  __syncthreads();
  const size_t base = ((size_t)b*30)*TL*NF + (size_t)t*NF;
  for (int e = threadIdx.x; e < 30*NF; e += 256){
    int k = e >> 7, n = e & 127;
    seq[base + (size_t)k*TL*NF + n] = tile[e];
  }
}

// ---- KW: one-time fp32 -> bf16 (hi, lo) split of all GEMM weights
__global__ __launch_bounds__(256) void k_wconv(
    const float* __restrict__ iw, const float* __restrict__ ow,
    const float* __restrict__ cw, const float* __restrict__ xw,
    ushort* __restrict__ wh, ushort* __restrict__ wl){
  const int idx = blockIdx.x*256 + threadIdx.x;
  if (idx >= WCNT) return;
  float v;
  if (idx < OFF_OW)       v = iw[idx];
  else if (idx < OFF_CBW) v = ow[idx - OFF_OW];
  else if (idx < OFF_XW)  v = cw[idx - OFF_CBW];
  else                    v = xw[idx - OFF_XW];
  const ushort h = bf16r(v);
  wh[idx] = h;
  wl[idx] = bf16r(v - bf2f(h));
}

// ---- K1 (known-good): LayerNorm + in_proj via MFMA bf16x3 split.
__global__ __launch_bounds__(256) void k_ln_inproj(
    const float* __restrict__ seq, const float* __restrict__ lnw, const float* __restrict__ lnb,
    const ushort* __restrict__ wh, const ushort* __restrict__ wl, const float* __restrict__ ib,
    float* __restrict__ xcr, float* __restrict__ zb){
  __shared__ short xsh[MT*NF];   // 16384 B
  __shared__ short xsl[MT*NF];   // 16384 B
  const int tid = threadIdx.x;
  const int tok0 = blockIdx.x * MT;

  {
    const int j = tid >> 4, l16 = tid & 15;
    for (int it = 0; it < 4; ++it){
      const int t = j + 16*it;
      const int tok = tok0 + t;
      float v[8]; float s = 0.f, s2 = 0.f;
      if (tok < NTOK){
        const float* sp = seq + (size_t)tok*NF;
        #pragma unroll
        for (int i = 0; i < 8; ++i){ float f = sp[l16 + 16*i]; v[i] = f; s += f; s2 += f*f; }
      } else {
        #pragma unroll
        for (int i = 0; i < 8; ++i) v[i] = 0.f;
      }
      #pragma unroll
      for (int m = 1; m < 16; m <<= 1){ s += __shfl_xor(s, m, 64); s2 += __shfl_xor(s2, m, 64); }
      const float mean = s * (1.f/128.f);
      const float rstd = rsqrtf(s2*(1.f/128.f) - mean*mean + 1e-5f);
      const int swz = (t & 7) << 3;
      #pragma unroll
      for (int i = 0; i < 8; ++i){
        const int n = l16 + 16*i;
        const float f = (v[i]-mean)*rstd*lnw[n] + lnb[n];
        const ushort h = bf16r(f);
        xsh[t*NF + (n ^ swz)] = (short)h;
        xsl[t*NF + (n ^ swz)] = (short)bf16r(f - bf2f(h));
      }
    }
  }
  __syncthreads();

  const int w = tid >> 6, lane = tid & 63;
  const int cl = lane & 15, q8 = (lane >> 4) * 8;
  const int obase = w * 64;
  f32x4 acc[4][4];
  #pragma unroll
  for (int m = 0; m < 4; ++m)
    #pragma unroll
    for (int nt = 0; nt < 4; ++nt) acc[m][nt] = (f32x4){0.f,0.f,0.f,0.f};

  for (int c = 0; c < 4; ++c){
    bf16x8 ah[4], al[4];
    #pragma unroll
    for (int m = 0; m < 4; ++m){
      const int r = m*16 + cl;
      const int hi = r*NF + ((c*32 + q8) ^ ((r & 7) << 3));
      ah[m] = *(const bf16x8*)&xsh[hi];
      al[m] = *(const bf16x8*)&xsl[hi];
    }
    #pragma unroll
    for (int nt = 0; nt < 4; ++nt){
      const int o = obase + nt*16 + cl;
      const size_t wo = (size_t)o*NF + c*32 + q8;
      const bf16x8 bh = *(const bf16x8*)(wh + wo);
      const bf16x8 bl = *(const bf16x8*)(wl + wo);
      #pragma unroll
      for (int m = 0; m < 4; ++m){
        acc[m][nt] = __builtin_amdgcn_mfma_f32_16x16x32_bf16(ah[m], bh, acc[m][nt], 0, 0, 0);
        acc[m][nt] = __builtin_amdgcn_mfma_f32_16x16x32_bf16(al[m], bh, acc[m][nt], 0, 0, 0);
        acc[m][nt] = __builtin_amdgcn_mfma_f32_16x16x32_bf16(ah[m], bl, acc[m][nt], 0, 0, 0);
      }
    }
  }

  const int rbase = (lane >> 4) * 4;
  #pragma unroll
  for (int nt = 0; nt < 4; ++nt){
    const int o = obase + nt*16 + cl;
    const float bias = ib[o];
    float* dst = (o < NF) ? xcr : zb;
    const int oc = (o < NF) ? o : (o - NF);
    #pragma unroll
    for (int m = 0; m < 4; ++m)
      #pragma unroll
      for (int j2 = 0; j2 < 4; ++j2){
        const int tok = tok0 + m*16 + rbase + j2;
        if (tok < NTOK) dst[(size_t)tok*NF + oc] = acc[m][nt][j2] + bias;
      }
  }
}

// ---- K2f (R9): conv+silu -> MFMA xproj -> dt -> scan pass 1.
// dtb (30.7MB) replaced by dcb ([tok][8], 1.9MB); dt recomputed in k_back.
__global__ __launch_bounds__(256) void k_conv_scan1(
    const float* __restrict__ xcr,
    const float* __restrict__ cw, const float* __restrict__ cb,
    const ushort* __restrict__ xwh, const ushort* __restrict__ xwl,
    const float* __restrict__ dw, const float* __restrict__ db,
    const float* __restrict__ alog,
    float* __restrict__ xcc, float* __restrict__ dcb,
    float* __restrict__ Bmb, float* __restrict__ Cmb,
    float* __restrict__ ap, float* __restrict__ hfb){
  __shared__ float smem[9600];                 // 38400 B
  float* sxr  = smem;                          // [35][128] f32 (stage->conv)
  float* sdt  = smem;                          // [32][128] f32 (dt->scan, aliases sxr)
  short* xch  = (short*)(smem + 4480);         // [32*128] bf16 hi (swizzled)
  short* xcl  = (short*)(smem + 6528);         // [32*128] bf16 lo
  float* sdbc = smem + 8576;                   // [32][32]
  const int bid = blockIdx.x;
  const int sq = bid / NCH, cblk = bid - sq*NCH;
  const int t0 = cblk*CLEN;
  const int lim = (TL - t0 < CLEN) ? (TL - t0) : CLEN;
  const int tid = threadIdx.x;

  for (int i = 0; i < 5; ++i){
    const int e4 = tid + i*256;
    if (e4 < 35*32){
      const int r = e4 >> 5, n4 = (e4 & 31) << 2;
      const int t = t0 - 3 + r;
      float4 v = make_float4(0.f,0.f,0.f,0.f);
      if (t >= 0 && t < TL) v = *(const float4*)(xcr + ((size_t)sq*TL + t)*NF + n4);
      *(float4*)(sxr + r*NF + n4) = v;
    }
  }
  __syncthreads();

  #pragma unroll
  for (int i = 0; i < 4; ++i){
    const int e4 = tid + i*256;
    const int r = e4 >> 5, n4 = (e4 & 31) << 2;
    const float4 c0 = *(const float4*)(cw + (size_t)(n4+0)*4);
    const float4 c1 = *(const float4*)(cw + (size_t)(n4+1)*4);
    const float4 c2 = *(const float4*)(cw + (size_t)(n4+2)*4);
    const float4 c3 = *(const float4*)(cw + (size_t)(n4+3)*4);
    const float4 x0 = *(const float4*)(sxr + (r+0)*NF + n4);
    const float4 x1 = *(const float4*)(sxr + (r+1)*NF + n4);
    const float4 x2 = *(const float4*)(sxr + (r+2)*NF + n4);
    const float4 x3 = *(const float4*)(sxr + (r+3)*NF + n4);
    float4 a = *(const float4*)(cb + n4);
    a.x = fmaf(x3.x, c0.w, fmaf(x2.x, c0.z, fmaf(x1.x, c0.y, fmaf(x0.x, c0.x, a.x))));
    a.y = fmaf(x3.y, c1.w, fmaf(x2.y, c1.z, fmaf(x1.y, c1.y, fmaf(x0.y, c1.x, a.y))));
    a.z = fmaf(x3.z, c2.w, fmaf(x2.z, c2.z, fmaf(x1.z, c2.y, fmaf(x0.z, c2.x, a.z))));
    a.w = fmaf(x3.w, c3.w, fmaf(x2.w, c3.z, fmaf(x1.w, c3.y, fmaf(x0.w, c3.x, a.w))));
    a.x = siluf(a.x); a.y = siluf(a.y); a.z = siluf(a.z); a.w = siluf(a.w);
    const ushort h0 = bf16r(a.x), h1 = bf16r(a.y), h2 = bf16r(a.z), h3 = bf16r(a.w);
    const ushort l0 = bf16r(a.x - bf2f(h0)), l1 = bf16r(a.y - bf2f(h1));
    const ushort l2 = bf16r(a.z - bf2f(h2)), l3 = bf16r(a.w - bf2f(h3));
    const int bi = r*NF + (n4 ^ ((r & 7) << 3));
    *(uint2*)&xch[bi] = make_uint2((uint)h0 | ((uint)h1 << 16), (uint)h2 | ((uint)h3 << 16));
    *(uint2*)&xcl[bi] = make_uint2((uint)l0 | ((uint)l1 << 16), (uint)l2 | ((uint)l3 << 16));
    if (r < lim) *(float4*)(xcc + ((size_t)sq*TL + t0 + r)*NF + n4) = a;
  }
  __syncthreads();

  // xproj via MFMA: dbc[32 tok][32 outs], K=128, bf16x3.
  {
    const int w = tid >> 6, lane = tid & 63;
    const int cl = lane & 15, q8 = (lane >> 4) * 8;
    const int m = w & 1, nt = w >> 1;
    f32x4 acc = (f32x4){0.f,0.f,0.f,0.f};
    for (int c = 0; c < 4; ++c){
      const int r = m*16 + cl;
      const int ai = r*NF + ((c*32 + q8) ^ ((r & 7) << 3));
      const bf16x8 ah = *(const bf16x8*)&xch[ai];
      const bf16x8 al = *(const bf16x8*)&xcl[ai];
      const int o = nt*16 + cl;
      const size_t wo = (size_t)o*NF + c*32 + q8;
      const bf16x8 bh = *(const bf16x8*)(xwh + wo);
      const bf16x8 bl = *(const bf16x8*)(xwl + wo);
      acc = __builtin_amdgcn_mfma_f32_16x16x32_bf16(ah, bh, acc, 0, 0, 0);
      acc = __builtin_amdgcn_mfma_f32_16x16x32_bf16(al, bh, acc, 0, 0, 0);
      acc = __builtin_amdgcn_mfma_f32_16x16x32_bf16(ah, bl, acc, 0, 0, 0);
    }
    const int rb = m*16 + (lane >> 4)*4;
    const int o = nt*16 + cl;
    #pragma unroll
    for (int j = 0; j < 4; ++j)
      sdbc[(rb + j)*32 + o] = acc[j];
  }
  __syncthreads();

  // dt (for local scan pass1 only) -> sdt
  #pragma unroll
  for (int i = 0; i < 16; ++i){
    const int e = tid + i*256;
    const int r = e >> 7, n = e & 127;
    const float4 b0 = *(const float4*)(sdbc + r*32);
    const float4 b1 = *(const float4*)(sdbc + r*32 + 4);
    const float4 w0 = *(const float4*)(dw + (size_t)n*8);
    const float4 w1 = *(const float4*)(dw + (size_t)n*8 + 4);
    float acc = db[n];
    acc = fmaf(b0.x, w0.x, acc); acc = fmaf(b0.y, w0.y, acc);
    acc = fmaf(b0.z, w0.z, acc); acc = fmaf(b0.w, w0.w, acc);
    acc = fmaf(b1.x, w1.x, acc); acc = fmaf(b1.y, w1.y, acc);
    acc = fmaf(b1.z, w1.z, acc); acc = fmaf(b1.w, w1.w, acc);
    sdt[e] = softplusf(acc);
  }
  // dcb + B/C global writes
  if (tid < 64){
    const int t = tid >> 1, q = tid & 1;
    if (t < lim)
      *(float4*)(dcb + ((size_t)sq*TL + t0 + t)*8 + q*4) = *(const float4*)&sdbc[t*32 + q*4];
  }
  for (int e = tid; e < CLEN*2*SD; e += 256){
    int r = e / (2*SD), c = e - r*2*SD;
    if (r < lim){
      float v = sdbc[r*32 + 8 + c];
      size_t tok = (size_t)sq*TL + t0 + r;
      if (c < SD) Bmb[tok*SD + c] = v;
      else        Cmb[tok*SD + (c - SD)] = v;
    }
  }
  __syncthreads();

  // scan pass 1 (power-trick dA with exact-exp fallback)
  {
    const int n = tid & 127, p = tid >> 7;
    float Av[6], h[6];
    #pragma unroll
    for (int s = 0; s < 6; ++s){
      Av[s] = -__expf(alog[(size_t)n*SD + p*6 + s]);
      h[s] = 0.f;
    }
    bool fast = true;
    #pragma unroll
    for (int s = 0; s < 6; ++s)
      fast = fast && (fabsf(Av[s] + (float)(p*6 + s + 1)) <= 1e-3f);
    float dts = 0.f;
    if (fast){
      for (int tt = 0; tt < lim; ++tt){
        const float dtv = sdt[tt*NF + n];
        const int xi = tt*NF + (n ^ ((tt & 7) << 3));
        const float xcv = bf2f((ushort)xch[xi]) + bf2f((ushort)xcl[xi]);
        float Bv[6];
        const float* br = sdbc + tt*32 + 8 + p*6;
        if (p == 0){
          const float4 a = *(const float4*)br;
          const float2 b = *(const float2*)(br + 4);
          Bv[0]=a.x; Bv[1]=a.y; Bv[2]=a.z; Bv[3]=a.w; Bv[4]=b.x; Bv[5]=b.y;
        } else {
          const float2 a = *(const float2*)br;
          const float4 b = *(const float4*)(br + 2);
          Bv[0]=a.x; Bv[1]=a.y; Bv[2]=b.x; Bv[3]=b.y; Bv[4]=b.z; Bv[5]=b.w;
        }
        const float dx = dtv * xcv;
        dts += dtv;
        const float q = __expf(-dtv);
        float dA;
        if (p == 0) dA = q;
        else { const float q2 = q*q; const float q4 = q2*q2; dA = q4*q2*q; }
        h[0] = fmaf(dA, h[0], dx*Bv[0]);
        #pragma unroll
        for (int s = 1; s < 6; ++s){ dA *= q; h[s] = fmaf(dA, h[s], dx*Bv[s]); }
      }
    } else {
      for (int tt = 0; tt < lim; ++tt){
        const float dtv = sdt[tt*NF + n];
        const int xi = tt*NF + (n ^ ((tt & 7) << 3));
        const float xcv = bf2f((ushort)xch[xi]) + bf2f((ushort)xcl[xi]);
        float Bv[6];
        const float* br = sdbc + tt*32 + 8 + p*6;
        if (p == 0){
          const float4 a = *(const float4*)br;
          const float2 b = *(const float2*)(br + 4);
          Bv[0]=a.x; Bv[1]=a.y; Bv[2]=a.z; Bv[3]=a.w; Bv[4]=b.x; Bv[5]=b.y;
        } else {
          const float2 a = *(const float2*)br;
          const float4 b = *(const float4*)(br + 2);
          Bv[0]=a.x; Bv[1]=a.y; Bv[2]=b.x; Bv[3]=b.y; Bv[4]=b.z; Bv[5]=b.w;
        }
        const float dx = dtv * xcv;
        dts += dtv;
        #pragma unroll
        for (int s = 0; s < 6; ++s){
          const float dA = __expf(dtv*Av[s]);
          h[s] = fmaf(dA, h[s], dx*Bv[s]);
        }
      }
    }
    const size_t base = (size_t)bid*SD*NF + n;
    #pragma unroll
    for (int s = 0; s < 6; ++s){
      ap [base + (p*6+s)*NF] = __expf(Av[s]*dts);
      hfb[base + (p*6+s)*NF] = h[s];
    }
  }
}

// ---- K3b: sequential combine across chunks
__global__ __launch_bounds__(128) void k_scan_combine(
    const float* __restrict__ ap, const float* __restrict__ hfb, float* __restrict__ hinit){
  const int sq = blockIdx.x;
  const int n = threadIdx.x;
  float h[SD];
  #pragma unroll
  for (int s = 0; s < SD; ++s) h[s] = 0.f;
  for (int c = 0; c < NCH; ++c){
    const size_t base = ((size_t)sq*NCH + c)*SD*NF + n;
    #pragma unroll
    for (int s = 0; s < SD; ++s){
      hinit[base + s*NF] = h[s];
      h[s] = fmaf(ap[base + s*NF], h[s], hfb[base + s*NF]);
    }
  }
}

// ---- k_back (R9): scan pass2 (dt recomputed from dcb; power-trick dA) + gate
// -> y into LDS as bf16 hi/lo -> MFMA GEMM -> seq += y @ ow^T + ob.
// 64-token tile (2 scan chunks), 960 blocks. Eliminates yb and dtb round-trips.
__global__ __launch_bounds__(256) void k_back(
    const float* __restrict__ dcb, const float* __restrict__ xcc,
    const float* __restrict__ Bmb, const float* __restrict__ Cmb,
    const float* __restrict__ zb,
    const ushort* __restrict__ wh, const ushort* __restrict__ wl,
    const float* __restrict__ dw, const float* __restrict__ db,
    const float* __restrict__ alog, const float* __restrict__ hinit,
    const float* __restrict__ Dv, const float* __restrict__ ob,
    float* __restrict__ seq){
  __shared__ short xsh[MT*NF];   // 16384 B
  __shared__ short xsl[MT*NF];   // 16384 B
  const int bid = blockIdx.x;
  const int sq = bid >> 4, cb2 = bid & 15;
  const int t0 = cb2 * MT;
  const int lim = (TL - t0 < MT) ? (TL - t0) : MT;
  const int tid = threadIdx.x;

  // P0: scan pass2 + gate -> LDS
  {
    const int n = tid & 127, ch = tid >> 7;
    float Av[SD];
    {
      const float4 a0 = *(const float4*)(alog + (size_t)n*SD);
      const float4 a1 = *(const float4*)(alog + (size_t)n*SD + 4);
      const float4 a2 = *(const float4*)(alog + (size_t)n*SD + 8);
      const float t_[SD] = {a0.x,a0.y,a0.z,a0.w, a1.x,a1.y,a1.z,a1.w, a2.x,a2.y,a2.z,a2.w};
      #pragma unroll
      for (int s = 0; s < SD; ++s) Av[s] = -__expf(t_[s]);
    }
    bool fast = true;
    #pragma unroll
    for (int s = 0; s < SD; ++s)
      fast = fast && (fabsf(Av[s] + (float)(s + 1)) <= 1e-3f);
    const float4 dw0 = *(const float4*)(dw + (size_t)n*8);
    const float4 dw1 = *(const float4*)(dw + (size_t)n*8 + 4);
    const float dbn = db[n];
    const float dvn = Dv[n];
    float h[SD];
    {
      const size_t hb = ((size_t)(sq*NCH + cb2*2 + ch))*SD*NF + n;
      #pragma unroll
      for (int s = 0; s < SD; ++s) h[s] = hinit[hb + s*NF];
    }
    int steps = lim - ch*32; if (steps < 0) steps = 0; if (steps > 32) steps = 32;
    for (int tt = 0; tt < steps; ++tt){
      const int t = ch*32 + tt;
      const size_t gt = (size_t)sq*TL + t0 + t;
      const float4 d0 = *(const float4*)(dcb + gt*8);
      const float4 d1 = *(const float4*)(dcb + gt*8 + 4);
      float da = dbn;
      da = fmaf(d0.x,dw0.x, da); da = fmaf(d0.y,dw0.y, da);
      da = fmaf(d0.z,dw0.z, da); da = fmaf(d0.w,dw0.w, da);
      da = fmaf(d1.x,dw1.x, da); da = fmaf(d1.y,dw1.y, da);
      da = fmaf(d1.z,dw1.z, da); da = fmaf(d1.w,dw1.w, da);
      const float dtv = softplusf(da);
      const float xcv = xcc[gt*NF + n];
      const float zv  = zb [gt*NF + n];
      const float4 B0 = *(const float4*)(Bmb + gt*SD);
      const float4 B1 = *(const float4*)(Bmb + gt*SD + 4);
      const float4 B2 = *(const float4*)(Bmb + gt*SD + 8);
      const float4 C0 = *(const float4*)(Cmb + gt*SD);
      const float4 C1 = *(const float4*)(Cmb + gt*SD + 4);
      const float4 C2 = *(const float4*)(Cmb + gt*SD + 8);
      const float Bv[SD] = {B0.x,B0.y,B0.z,B0.w, B1.x,B1.y,B1.z,B1.w, B2.x,B2.y,B2.z,B2.w};
      const float Cv[SD] = {C0.x,C0.y,C0.z,C0.w, C1.x,C1.y,C1.z,C1.w, C2.x,C2.y,C2.z,C2.w};
      const float dx = dtv * xcv;
      float yv = 0.f;
      if (fast){
        const float q = __expf(-dtv);
        float dA = q;
        h[0] = fmaf(dA, h[0], dx*Bv[0]);
        yv = fmaf(h[0], Cv[0], yv);
        #pragma unroll
        for (int s = 1; s < SD; ++s){
          dA *= q;
          h[s] = fmaf(dA, h[s], dx*Bv[s]);
          yv = fmaf(h[s], Cv[s], yv);
        }
      } else {
        #pragma unroll
        for (int s = 0; s < SD; ++s){
          const float dA = __expf(dtv*Av[s]);
          h[s] = fmaf(dA, h[s], dx*Bv[s]);
          yv = fmaf(h[s], Cv[s], yv);
        }
      }
      const float yf = fmaf(dvn, xcv, yv) * siluf(zv);
      const ushort hh = bf16r(yf);
      const int bi = t*NF + (n ^ ((t & 7) << 3));
      xsh[bi] = (short)hh;
      xsl[bi] = (short)bf16r(yf - bf2f(hh));
    }
  }
  if (lim < MT){
    for (int e = tid; e < (MT - lim)*NF; e += 256){ xsh[lim*NF + e] = 0; xsl[lim*NF + e] = 0; }
  }
  __syncthreads();

  // P1: MFMA GEMM seq += y @ ow^T + ob (bf16x3)
  const int w = tid >> 6, lane = tid & 63;
  const int cl = lane & 15, q8 = (lane >> 4) * 8;
  const int obase = w * 32;
  f32x4 acc[4][2];
  #pragma unroll
  for (int m = 0; m < 4; ++m)
    #pragma unroll
    for (int nt = 0; nt < 2; ++nt) acc[m][nt] = (f32x4){0.f,0.f,0.f,0.f};

  for (int c = 0; c < 4; ++c){
    bf16x8 ah[4], al[4];
    #pragma unroll
    for (int m = 0; m < 4; ++m){
      const int r = m*16 + cl;
      const int hi = r*NF + ((c*32 + q8) ^ ((r & 7) << 3));
      ah[m] = *(const bf16x8*)&xsh[hi];
      al[m] = *(const bf16x8*)&xsl[hi];
    }
    #pragma unroll
    for (int nt = 0; nt < 2; ++nt){
      const int o = obase + nt*16 + cl;
      const size_t wo = (size_t)o*NF + c*32 + q8;
      const bf16x8 bh = *(const bf16x8*)(wh + wo);
      const bf16x8 bl = *(const bf16x8*)(wl + wo);
      #pragma unroll
      for (int m = 0; m < 4; ++m){
        acc[m][nt] = __builtin_amdgcn_mfma_f32_16x16x32_bf16(ah[m], bh, acc[m][nt], 0, 0, 0);
        acc[m][nt] = __builtin_amdgcn_mfma_f32_16x16x32_bf16(al[m], bh, acc[m][nt], 0, 0, 0);
        acc[m][nt] = __builtin_amdgcn_mfma_f32_16x16x32_bf16(ah[m], bl, acc[m][nt], 0, 0, 0);
      }
    }
  }

  const int rbase = (lane >> 4) * 4;
  #pragma unroll
  for (int nt = 0; nt < 2; ++nt){
    const int o = obase + nt*16 + cl;
    const float bias = ob[o];
    #pragma unroll
    for (int m = 0; m < 4; ++m)
      #pragma unroll
      for (int j2 = 0; j2 < 4; ++j2){
        const int lt = m*16 + rbase + j2;
        if (lt < lim){
          float* dst = seq + ((size_t)sq*TL + t0 + lt)*NF + o;
          *dst = *dst + acc[m][nt][j2] + bias;
        }
      }
  }
}

// ---- K5a (known-good): cross = main @ cb_w^T + cb_b via MFMA bf16x3.
__global__ __launch_bounds__(256) void k_cross_gemm(
    const float* __restrict__ seq,
    const ushort* __restrict__ wh, const ushort* __restrict__ wl, const float* __restrict__ cbb,
    float* __restrict__ cross){
  __shared__ short xsh[MT*NF];
  __shared__ short xsl[MT*NF];
  const int tid = threadIdx.x;
  const int tok0 = blockIdx.x * MT;

  #pragma unroll
  for (int i = 0; i < 8; ++i){
    const int r  = (tid & 15) + ((i & 3) << 4);
    const int nq = (tid >> 4) + ((i >> 2) << 4);
    const int tok = tok0 + r;
    float4 v = make_float4(0.f,0.f,0.f,0.f);
    if (tok < NTOK){
      int b = tok / 30000, rr = tok - b*30000;
      int t = rr / 30, k = rr - t*30;
      v = *(const float4*)(seq + ((size_t)(b*30 + k)*TL + t)*NF + nq*4);
    }
    const ushort h0 = bf16r(v.x), h1 = bf16r(v.y), h2 = bf16r(v.z), h3 = bf16r(v.w);
    const ushort l0 = bf16r(v.x - bf2f(h0)), l1 = bf16r(v.y - bf2f(h1));
    const ushort l2 = bf16r(v.z - bf2f(h2)), l3 = bf16r(v.w - bf2f(h3));
    const int hi = r*NF + ((nq*4) ^ ((r & 7) << 3));
    *(uint2*)&xsh[hi] = make_uint2((uint)h0 | ((uint)h1 << 16), (uint)h2 | ((uint)h3 << 16));
    *(uint2*)&xsl[hi] = make_uint2((uint)l0 | ((uint)l1 << 16), (uint)l2 | ((uint)l3 << 16));
  }
  __syncthreads();

  const int w = tid >> 6, lane = tid & 63;
  const int cl = lane & 15, q8 = (lane >> 4) * 8;
  const int obase = w * 32;
  f32x4 acc[4][2];
  #pragma unroll
  for (int m = 0; m < 4; ++m)
    #pragma unroll
    for (int nt = 0; nt < 2; ++nt) acc[m][nt] = (f32x4){0.f,0.f,0.f,0.f};

  for (int c = 0; c < 4; ++c){
    bf16x8 ah[4], al[4];
    #pragma unroll
    for (int m = 0; m < 4; ++m){
      const int r = m*16 + cl;
      const int hi = r*NF + ((c*32 + q8) ^ ((r & 7) << 3));
      ah[m] = *(const bf16x8*)&xsh[hi];
      al[m] = *(const bf16x8*)&xsl[hi];
    }
    #pragma unroll
    for (int nt = 0; nt < 2; ++nt){
      const int o = obase + nt*16 + cl;
      const size_t wo = (size_t)o*NF + c*32 + q8;
      const bf16x8 bh = *(const bf16x8*)(wh + wo);
      const bf16x8 bl = *(const bf16x8*)(wl + wo);
      #pragma unroll
      for (int m = 0; m < 4; ++m){
        acc[m][nt] = __builtin_amdgcn_mfma_f32_16x16x32_bf16(ah[m], bh, acc[m][nt], 0, 0, 0);
        acc[m][nt] = __builtin_amdgcn_mfma_f32_16x16x32_bf16(al[m], bh, acc[m][nt], 0, 0, 0);
        acc[m][nt] = __builtin_amdgcn_mfma_f32_16x16x32_bf16(ah[m], bl, acc[m][nt], 0, 0, 0);
      }
    }
  }

  const int rbase = (lane >> 4) * 4;
  #pragma unroll
  for (int nt = 0; nt < 2; ++nt){
    const int o = obase + nt*16 + cl;
    const float bias = cbb[o];
    #pragma unroll
    for (int m = 0; m < 4; ++m)
      #pragma unroll
      for (int j2 = 0; j2 < 4; ++j2){
        const int tok = tok0 + m*16 + rbase + j2;
        if (tok < NTOK) cross[(size_t)tok*NF + o] = acc[m][nt][j2] + bias;
      }
  }
}

// ---- K5b: LN1 -> gelu -> +main -> LN2 -> transposed write. 32 tokens/block.
__global__ __launch_bounds__(256) void k_cross_ln(
    const float* __restrict__ seq, const float* __restrict__ cross,
    const float* __restrict__ clnw, const float* __restrict__ clnb,
    const float* __restrict__ flnw, const float* __restrict__ flnb,
    float* __restrict__ out){
  __shared__ float fs[32*LNP];
  const int tid = threadIdx.x;
  const int tok0 = blockIdx.x * 32;
  const int j16 = tid >> 4, l16 = tid & 15;

  for (int it = 0; it < 2; ++it){
    const int jj = j16 + 16*it;
    const int tok = tok0 + jj;
    const int b = tok / 30000, rr = tok - b*30000;
    const int t = rr / 30, k = rr - t*30;
    const float* cp = cross + (size_t)tok*NF;
    const float* mp = seq + ((size_t)(b*30 + k)*TL + t)*NF;
    float cv[8]; float s = 0.f, s2 = 0.f;
    #pragma unroll
    for (int i = 0; i < 8; ++i){
      float f = cp[l16 + 16*i]; cv[i] = f; s += f; s2 += f*f;
    }
    #pragma unroll
    for (int m = 1; m < 16; m <<= 1){ s += __shfl_xor(s, m, 64); s2 += __shfl_xor(s2, m, 64); }
    float mu = s * (1.f/128.f);
    float rs = rsqrtf(s2*(1.f/128.f) - mu*mu + 1e-5f);
    float rv[8]; float rsum = 0.f, rsum2 = 0.f;
    #pragma unroll
    for (int i = 0; i < 8; ++i){
      int n = l16 + 16*i;
      float cn = (cv[i] - mu)*rs*clnw[n] + clnb[n];
      float g = 0.5f*cn*(1.f + erff(cn*0.70710678118f));
      float res = mp[n] + g;
      rv[i] = res; rsum += res; rsum2 += res*res;
    }
    #pragma unroll
    for (int m = 1; m < 16; m <<= 1){ rsum += __shfl_xor(rsum, m, 64); rsum2 += __shfl_xor(rsum2, m, 64); }
    float mu2 = rsum * (1.f/128.f);
    float rs2 = rsqrtf(rsum2*(1.f/128.f) - mu2*mu2 + 1e-5f);
    #pragma unroll
    for (int i = 0; i < 8; ++i){
      int n = l16 + 16*i;
      fs[jj*LNP + n] = (rv[i] - mu2)*rs2*flnw[n] + flnb[n];
    }
  }
  __syncthreads();

  #pragma unroll
  for (int i = 0; i < 16; ++i){
    const int e = tid + i*256;
    const int j = e & 31, n = e >> 5;
    const int tok = tok0 + j;
    const int b = tok / 30000, rr = tok - b*30000;
    out[(size_t)(b*NF + n)*30000 + rr] = fs[j*LNP + n];
  }
}

extern "C" void kernel_launch(void* const* d_in, const int* in_sizes, int n_in,
                              void* d_out, int out_size, void* d_ws, size_t ws_size,
                              hipStream_t stream){
  const float* x       = (const float*)d_in[0];
  const float* ln_w    = (const float*)d_in[1];
  const float* ln_b    = (const float*)d_in[2];
  const float* in_w    = (const float*)d_in[3];
  const float* in_b    = (const float*)d_in[4];
  const float* conv_w  = (const float*)d_in[5];
  const float* conv_b  = (const float*)d_in[6];
  const float* xp_w    = (const float*)d_in[7];
  const float* dtp_w   = (const float*)d_in[8];
  const float* dtp_b   = (const float*)d_in[9];
  const float* A_log   = (const float*)d_in[10];
  const float* Dv      = (const float*)d_in[11];
  const float* out_w   = (const float*)d_in[12];
  const float* out_b   = (const float*)d_in[13];
  const float* cb_w    = (const float*)d_in[14];
  const float* cb_b    = (const float*)d_in[15];
  const float* cb_ln_w = (const float*)d_in[16];
  const float* cb_ln_b = (const float*)d_in[17];
  const float* fin_ln_w= (const float*)d_in[18];
  const float* fin_ln_b= (const float*)d_in[19];
  float* out = (float*)d_out;

  const size_t SEQSZ = (size_t)BKS*TL*NF;        // 7,680,000 floats
  const size_t CHSZ  = (size_t)BKS*NF*NCH*SD;    // 2,949,120 floats
  const size_t FBASE = 6*SEQSZ + 2*(size_t)BKS*TL*SD;   // fp32 region
  const size_t BASE  = FBASE + WCNT;                    // + bf16 pool (2*WCNT ushorts)
  float* ws  = (float*)d_ws;
  float* seq = ws;
  float* xcr = ws + SEQSZ;
  float* zb  = ws + 2*SEQSZ;
  float* xcc = ws + 3*SEQSZ;
  float* dcb = ws + 4*SEQSZ;        // [tok][8]; dead before cross_gemm
  float* scr = ws + 5*SEQSZ;        // ap/hfb scratch
  float* Bmb = ws + 6*SEQSZ;
  float* Cmb = Bmb + (size_t)BKS*TL*SD;
  ushort* wbh = (ushort*)(ws + FBASE);
  ushort* wbl = wbh + WCNT;
  if (ws_size < BASE*sizeof(float)) return;

  // Liveness aliasing: ap/hfb -> scr; hinit -> xcr; cross -> dcb region.
  float* ap    = scr;
  float* hfb   = scr + CHSZ;
  float* hinit = xcr;
  float* cross = dcb;

  k_wconv<<<(WCNT + 255)/256, 256, 0, stream>>>(in_w, out_w, cb_w, xp_w, wbh, wbl);
  k_ingest<<<2*TL, 256, 0, stream>>>(x, seq);
  for (int l = 0; l < 4; ++l){
    k_ln_inproj<<<NBLK, 256, 0, stream>>>(seq, ln_w + l*NF, ln_b + l*NF,
        wbh + (size_t)l*32768, wbl + (size_t)l*32768, in_b + l*2*NF, xcr, zb);
    k_conv_scan1<<<BKS*NCH, 256, 0, stream>>>(xcr, conv_w + (size_t)l*NF*4, conv_b + l*NF,
        wbh + OFF_XW + (size_t)l*4096, wbl + OFF_XW + (size_t)l*4096,
        dtp_w + (size_t)l*NF*RD, dtp_b + l*NF,
        A_log + (size_t)l*NF*SD, xcc, dcb, Bmb, Cmb, ap, hfb);
    k_scan_combine<<<BKS, NF, 0, stream>>>(ap, hfb, hinit);
    k_back<<<BKS*16, 256, 0, stream>>>(dcb, xcc, Bmb, Cmb, zb,
        wbh + OFF_OW + (size_t)l*16384, wbl + OFF_OW + (size_t)l*16384,
        dtp_w + (size_t)l*NF*RD, dtp_b + l*NF,
        A_log + (size_t)l*NF*SD, hinit, Dv + l*NF, out_b + l*NF, seq);
  }
  k_cross_gemm<<<NBLK, 256, 0, stream>>>(seq, wbh + OFF_CBW, wbl + OFF_CBW, cb_b, cross);
  k_cross_ln<<<NTOK/32, 256, 0, stream>>>(seq, cross, cb_ln_w, cb_ln_b, fin_ln_w, fin_ln_b, out);
}

// Round 10
// 726.330 us; speedup vs baseline: 1.1859x; 1.1859x over previous
//
#include <hip/hip_runtime.h>
#include <math.h>

#define BKS 60      // B*K sequences
#define TL  1000    // T
#define NF  128     // N features
#define SD  12      // state dim S
#define RD  8       // dt rank
#define NCH 32      // scan chunks
#define CLEN 32     // chunk length
#define NTOK (BKS*TL)
#define MT  64      // GEMM token tile
#define NBLK ((NTOK + MT - 1)/MT)   // 938
#define LNP 129     // cross_ln LDS stride
// bf16 weight pool: in_w 131072 | out_w 65536 | cb_w 16384 | xp_w 16384
#define OFF_OW  131072
#define OFF_CBW 196608
#define OFF_XW  212992
#define WCNT    229376

typedef __bf16 bf16x8 __attribute__((ext_vector_type(8)));
typedef float  f32x4  __attribute__((ext_vector_type(4)));

__device__ __forceinline__ float siluf(float x){ return x / (1.f + __expf(-x)); }
__device__ __forceinline__ float softplusf(float x){
  if (x > 20.f) return x;
  float e = __expf(x);
  return (x < -20.f) ? e : __logf(1.f + e);
}
__device__ __forceinline__ ushort bf16r(float f){          // RNE fp32->bf16
  uint u = __float_as_uint(f);
  return (ushort)((u + 0x7FFFu + ((u>>16)&1u)) >> 16);
}
__device__ __forceinline__ float bf2f(ushort h){ return __uint_as_float(((uint)h)<<16); }

// ---- K0: x (B,N,T,K) -> seq (B*K, T, N)
__global__ __launch_bounds__(256) void k_ingest(const float* __restrict__ x, float* __restrict__ seq){
  const int b = blockIdx.x / TL, t = blockIdx.x % TL;
  __shared__ float tile[30*NF];
  for (int e = threadIdx.x; e < 30*NF; e += 256){
    int n = e / 30, k = e - n*30;
    tile[k*NF + n] = x[((size_t)(b*NF + n)*TL + t)*30 + k];
  }
  __syncthreads();
  const size_t base = ((size_t)b*30)*TL*NF + (size_t)t*NF;
  for (int e = threadIdx.x; e < 30*NF; e += 256){
    int k = e >> 7, n = e & 127;
    seq[base + (size_t)k*TL*NF + n] = tile[e];
  }
}

// ---- KW: one-time fp32 -> bf16 (hi, lo) split of all GEMM weights
__global__ __launch_bounds__(256) void k_wconv(
    const float* __restrict__ iw, const float* __restrict__ ow,
    const float* __restrict__ cw, const float* __restrict__ xw,
    ushort* __restrict__ wh, ushort* __restrict__ wl){
  const int idx = blockIdx.x*256 + threadIdx.x;
  if (idx >= WCNT) return;
  float v;
  if (idx < OFF_OW)       v = iw[idx];
  else if (idx < OFF_CBW) v = ow[idx - OFF_OW];
  else if (idx < OFF_XW)  v = cw[idx - OFF_CBW];
  else                    v = xw[idx - OFF_XW];
  const ushort h = bf16r(v);
  wh[idx] = h;
  wl[idx] = bf16r(v - bf2f(h));
}

// ---- K1 (R10): LayerNorm + in_proj via MFMA bf16x3 split.
// LN staging vectorized: each thread owns a contiguous 8-feature slice ->
// 2x float4 load + 2x uint4 store per token-row (was 8 scalar dword loads +
// 16 scalar short stores). Swizzle (t&7)<<3 only flips bits >=3 of n, so the
// 8-slice stays 16B-contiguous after XOR.
__global__ __launch_bounds__(256) void k_ln_inproj(
    const float* __restrict__ seq, const float* __restrict__ lnw, const float* __restrict__ lnb,
    const ushort* __restrict__ wh, const ushort* __restrict__ wl, const float* __restrict__ ib,
    float* __restrict__ xcr, float* __restrict__ zb){
  __shared__ short xsh[MT*NF];   // 16384 B
  __shared__ short xsl[MT*NF];   // 16384 B
  const int tid = threadIdx.x;
  const int tok0 = blockIdx.x * MT;

  {
    const int j = tid >> 4, l16 = tid & 15;
    const float4 w0 = *(const float4*)(lnw + l16*8);
    const float4 w1 = *(const float4*)(lnw + l16*8 + 4);
    const float4 b0 = *(const float4*)(lnb + l16*8);
    const float4 b1 = *(const float4*)(lnb + l16*8 + 4);
    const float lw[8] = {w0.x,w0.y,w0.z,w0.w, w1.x,w1.y,w1.z,w1.w};
    const float lb[8] = {b0.x,b0.y,b0.z,b0.w, b1.x,b1.y,b1.z,b1.w};
    for (int it = 0; it < 4; ++it){
      const int t = j + 16*it;
      const int tok = tok0 + t;
      float v[8]; float s = 0.f, s2 = 0.f;
      if (tok < NTOK){
        const float* sp = seq + (size_t)tok*NF + l16*8;
        const float4 a0 = *(const float4*)sp;
        const float4 a1 = *(const float4*)(sp + 4);
        v[0]=a0.x; v[1]=a0.y; v[2]=a0.z; v[3]=a0.w;
        v[4]=a1.x; v[5]=a1.y; v[6]=a1.z; v[7]=a1.w;
        #pragma unroll
        for (int i = 0; i < 8; ++i){ s += v[i]; s2 += v[i]*v[i]; }
      } else {
        #pragma unroll
        for (int i = 0; i < 8; ++i) v[i] = 0.f;
      }
      #pragma unroll
      for (int m = 1; m < 16; m <<= 1){ s += __shfl_xor(s, m, 64); s2 += __shfl_xor(s2, m, 64); }
      const float mean = s * (1.f/128.f);
      const float rstd = rsqrtf(s2*(1.f/128.f) - mean*mean + 1e-5f);
      const int swz = (t & 7) << 3;
      const int nb = (l16*8) ^ swz;          // contiguous 8, 16B-aligned
      ushort hs[8], ls[8];
      #pragma unroll
      for (int i = 0; i < 8; ++i){
        const float f = (v[i]-mean)*rstd*lw[i] + lb[i];
        const ushort h = bf16r(f);
        hs[i] = h;
        ls[i] = bf16r(f - bf2f(h));
      }
      uint4 hv, lv;
      hv.x = (uint)hs[0] | ((uint)hs[1] << 16); hv.y = (uint)hs[2] | ((uint)hs[3] << 16);
      hv.z = (uint)hs[4] | ((uint)hs[5] << 16); hv.w = (uint)hs[6] | ((uint)hs[7] << 16);
      lv.x = (uint)ls[0] | ((uint)ls[1] << 16); lv.y = (uint)ls[2] | ((uint)ls[3] << 16);
      lv.z = (uint)ls[4] | ((uint)ls[5] << 16); lv.w = (uint)ls[6] | ((uint)ls[7] << 16);
      *(uint4*)&xsh[t*NF + nb] = hv;
      *(uint4*)&xsl[t*NF + nb] = lv;
    }
  }
  __syncthreads();

  const int w = tid >> 6, lane = tid & 63;
  const int cl = lane & 15, q8 = (lane >> 4) * 8;
  const int obase = w * 64;
  f32x4 acc[4][4];
  #pragma unroll
  for (int m = 0; m < 4; ++m)
    #pragma unroll
    for (int nt = 0; nt < 4; ++nt) acc[m][nt] = (f32x4){0.f,0.f,0.f,0.f};

  for (int c = 0; c < 4; ++c){
    bf16x8 ah[4], al[4];
    #pragma unroll
    for (int m = 0; m < 4; ++m){
      const int r = m*16 + cl;
      const int hi = r*NF + ((c*32 + q8) ^ ((r & 7) << 3));
      ah[m] = *(const bf16x8*)&xsh[hi];
      al[m] = *(const bf16x8*)&xsl[hi];
    }
    #pragma unroll
    for (int nt = 0; nt < 4; ++nt){
      const int o = obase + nt*16 + cl;
      const size_t wo = (size_t)o*NF + c*32 + q8;
      const bf16x8 bh = *(const bf16x8*)(wh + wo);
      const bf16x8 bl = *(const bf16x8*)(wl + wo);
      #pragma unroll
      for (int m = 0; m < 4; ++m){
        acc[m][nt] = __builtin_amdgcn_mfma_f32_16x16x32_bf16(ah[m], bh, acc[m][nt], 0, 0, 0);
        acc[m][nt] = __builtin_amdgcn_mfma_f32_16x16x32_bf16(al[m], bh, acc[m][nt], 0, 0, 0);
        acc[m][nt] = __builtin_amdgcn_mfma_f32_16x16x32_bf16(ah[m], bl, acc[m][nt], 0, 0, 0);
      }
    }
  }

  const int rbase = (lane >> 4) * 4;
  #pragma unroll
  for (int nt = 0; nt < 4; ++nt){
    const int o = obase + nt*16 + cl;
    const float bias = ib[o];
    float* dst = (o < NF) ? xcr : zb;
    const int oc = (o < NF) ? o : (o - NF);
    #pragma unroll
    for (int m = 0; m < 4; ++m)
      #pragma unroll
      for (int j2 = 0; j2 < 4; ++j2){
        const int tok = tok0 + m*16 + rbase + j2;
        if (tok < NTOK) dst[(size_t)tok*NF + oc] = acc[m][nt][j2] + bias;
      }
  }
}

// ---- K2f (R8 known-good): conv+silu -> MFMA xproj -> dt -> scan pass 1
// (power-trick dA with exact-exp fallback).
__global__ __launch_bounds__(256) void k_conv_scan1(
    const float* __restrict__ xcr,
    const float* __restrict__ cw, const float* __restrict__ cb,
    const ushort* __restrict__ xwh, const ushort* __restrict__ xwl,
    const float* __restrict__ dw, const float* __restrict__ db,
    const float* __restrict__ alog,
    float* __restrict__ xcc, float* __restrict__ dtb,
    float* __restrict__ Bmb, float* __restrict__ Cmb,
    float* __restrict__ ap, float* __restrict__ hfb){
  __shared__ float smem[9600];                 // 38400 B
  float* sxr  = smem;                          // [35][128] f32 (stage->conv)
  float* sdt  = smem;                          // [32][128] f32 (dt->scan, aliases sxr)
  short* xch  = (short*)(smem + 4480);         // [32*128] bf16 hi (swizzled)
  short* xcl  = (short*)(smem + 6528);         // [32*128] bf16 lo
  float* sdbc = smem + 8576;                   // [32][32]
  const int bid = blockIdx.x;
  const int sq = bid / NCH, cblk = bid - sq*NCH;
  const int t0 = cblk*CLEN;
  const int lim = (TL - t0 < CLEN) ? (TL - t0) : CLEN;
  const int tid = threadIdx.x;

  for (int i = 0; i < 5; ++i){
    const int e4 = tid + i*256;
    if (e4 < 35*32){
      const int r = e4 >> 5, n4 = (e4 & 31) << 2;
      const int t = t0 - 3 + r;
      float4 v = make_float4(0.f,0.f,0.f,0.f);
      if (t >= 0 && t < TL) v = *(const float4*)(xcr + ((size_t)sq*TL + t)*NF + n4);
      *(float4*)(sxr + r*NF + n4) = v;
    }
  }
  __syncthreads();

  #pragma unroll
  for (int i = 0; i < 4; ++i){
    const int e4 = tid + i*256;
    const int r = e4 >> 5, n4 = (e4 & 31) << 2;
    const float4 c0 = *(const float4*)(cw + (size_t)(n4+0)*4);
    const float4 c1 = *(const float4*)(cw + (size_t)(n4+1)*4);
    const float4 c2 = *(const float4*)(cw + (size_t)(n4+2)*4);
    const float4 c3 = *(const float4*)(cw + (size_t)(n4+3)*4);
    const float4 x0 = *(const float4*)(sxr + (r+0)*NF + n4);
    const float4 x1 = *(const float4*)(sxr + (r+1)*NF + n4);
    const float4 x2 = *(const float4*)(sxr + (r+2)*NF + n4);
    const float4 x3 = *(const float4*)(sxr + (r+3)*NF + n4);
    float4 a = *(const float4*)(cb + n4);
    a.x = fmaf(x3.x, c0.w, fmaf(x2.x, c0.z, fmaf(x1.x, c0.y, fmaf(x0.x, c0.x, a.x))));
    a.y = fmaf(x3.y, c1.w, fmaf(x2.y, c1.z, fmaf(x1.y, c1.y, fmaf(x0.y, c1.x, a.y))));
    a.z = fmaf(x3.z, c2.w, fmaf(x2.z, c2.z, fmaf(x1.z, c2.y, fmaf(x0.z, c2.x, a.z))));
    a.w = fmaf(x3.w, c3.w, fmaf(x2.w, c3.z, fmaf(x1.w, c3.y, fmaf(x0.w, c3.x, a.w))));
    a.x = siluf(a.x); a.y = siluf(a.y); a.z = siluf(a.z); a.w = siluf(a.w);
    const ushort h0 = bf16r(a.x), h1 = bf16r(a.y), h2 = bf16r(a.z), h3 = bf16r(a.w);
    const ushort l0 = bf16r(a.x - bf2f(h0)), l1 = bf16r(a.y - bf2f(h1));
    const ushort l2 = bf16r(a.z - bf2f(h2)), l3 = bf16r(a.w - bf2f(h3));
    const int bi = r*NF + (n4 ^ ((r & 7) << 3));
    *(uint2*)&xch[bi] = make_uint2((uint)h0 | ((uint)h1 << 16), (uint)h2 | ((uint)h3 << 16));
    *(uint2*)&xcl[bi] = make_uint2((uint)l0 | ((uint)l1 << 16), (uint)l2 | ((uint)l3 << 16));
    if (r < lim) *(float4*)(xcc + ((size_t)sq*TL + t0 + r)*NF + n4) = a;
  }
  __syncthreads();

  // xproj via MFMA: dbc[32 tok][32 outs], K=128, bf16x3.
  {
    const int w = tid >> 6, lane = tid & 63;
    const int cl = lane & 15, q8 = (lane >> 4) * 8;
    const int m = w & 1, nt = w >> 1;
    f32x4 acc = (f32x4){0.f,0.f,0.f,0.f};
    for (int c = 0; c < 4; ++c){
      const int r = m*16 + cl;
      const int ai = r*NF + ((c*32 + q8) ^ ((r & 7) << 3));
      const bf16x8 ah = *(const bf16x8*)&xch[ai];
      const bf16x8 al = *(const bf16x8*)&xcl[ai];
      const int o = nt*16 + cl;
      const size_t wo = (size_t)o*NF + c*32 + q8;
      const bf16x8 bh = *(const bf16x8*)(xwh + wo);
      const bf16x8 bl = *(const bf16x8*)(xwl + wo);
      acc = __builtin_amdgcn_mfma_f32_16x16x32_bf16(ah, bh, acc, 0, 0, 0);
      acc = __builtin_amdgcn_mfma_f32_16x16x32_bf16(al, bh, acc, 0, 0, 0);
      acc = __builtin_amdgcn_mfma_f32_16x16x32_bf16(ah, bl, acc, 0, 0, 0);
    }
    const int rb = m*16 + (lane >> 4)*4;
    const int o = nt*16 + cl;
    #pragma unroll
    for (int j = 0; j < 4; ++j)
      sdbc[(rb + j)*32 + o] = acc[j];
  }
  __syncthreads();

  // dt = softplus(dbc[:, :8] @ dw^T + db) -> sdt + dtb global
  #pragma unroll
  for (int i = 0; i < 16; ++i){
    const int e = tid + i*256;
    const int r = e >> 7, n = e & 127;
    const float4 b0 = *(const float4*)(sdbc + r*32);
    const float4 b1 = *(const float4*)(sdbc + r*32 + 4);
    const float4 w0 = *(const float4*)(dw + (size_t)n*8);
    const float4 w1 = *(const float4*)(dw + (size_t)n*8 + 4);
    float acc = db[n];
    acc = fmaf(b0.x, w0.x, acc); acc = fmaf(b0.y, w0.y, acc);
    acc = fmaf(b0.z, w0.z, acc); acc = fmaf(b0.w, w0.w, acc);
    acc = fmaf(b1.x, w1.x, acc); acc = fmaf(b1.y, w1.y, acc);
    acc = fmaf(b1.z, w1.z, acc); acc = fmaf(b1.w, w1.w, acc);
    const float dtv = softplusf(acc);
    sdt[e] = dtv;
    if (e < lim*NF) dtb[((size_t)sq*TL + t0)*NF + e] = dtv;
  }
  // B/C global writes
  for (int e = tid; e < CLEN*2*SD; e += 256){
    int r = e / (2*SD), c = e - r*2*SD;
    if (r < lim){
      float v = sdbc[r*32 + 8 + c];
      size_t tok = (size_t)sq*TL + t0 + r;
      if (c < SD) Bmb[tok*SD + c] = v;
      else        Cmb[tok*SD + (c - SD)] = v;
    }
  }
  __syncthreads();

  // scan pass 1 (power-trick dA with exact-exp fallback)
  {
    const int n = tid & 127, p = tid >> 7;
    float Av[6], h[6];
    #pragma unroll
    for (int s = 0; s < 6; ++s){
      Av[s] = -__expf(alog[(size_t)n*SD + p*6 + s]);
      h[s] = 0.f;
    }
    bool fast = true;
    #pragma unroll
    for (int s = 0; s < 6; ++s)
      fast = fast && (fabsf(Av[s] + (float)(p*6 + s + 1)) <= 1e-3f);
    float dts = 0.f;
    if (fast){
      for (int tt = 0; tt < lim; ++tt){
        const float dtv = sdt[tt*NF + n];
        const int xi = tt*NF + (n ^ ((tt & 7) << 3));
        const float xcv = bf2f((ushort)xch[xi]) + bf2f((ushort)xcl[xi]);
        float Bv[6];
        const float* br = sdbc + tt*32 + 8 + p*6;
        if (p == 0){
          const float4 a = *(const float4*)br;
          const float2 b = *(const float2*)(br + 4);
          Bv[0]=a.x; Bv[1]=a.y; Bv[2]=a.z; Bv[3]=a.w; Bv[4]=b.x; Bv[5]=b.y;
        } else {
          const float2 a = *(const float2*)br;
          const float4 b = *(const float4*)(br + 2);
          Bv[0]=a.x; Bv[1]=a.y; Bv[2]=b.x; Bv[3]=b.y; Bv[4]=b.z; Bv[5]=b.w;
        }
        const float dx = dtv * xcv;
        dts += dtv;
        const float q = __expf(-dtv);
        float dA;
        if (p == 0) dA = q;
        else { const float q2 = q*q; const float q4 = q2*q2; dA = q4*q2*q; }
        h[0] = fmaf(dA, h[0], dx*Bv[0]);
        #pragma unroll
        for (int s = 1; s < 6; ++s){ dA *= q; h[s] = fmaf(dA, h[s], dx*Bv[s]); }
      }
    } else {
      for (int tt = 0; tt < lim; ++tt){
        const float dtv = sdt[tt*NF + n];
        const int xi = tt*NF + (n ^ ((tt & 7) << 3));
        const float xcv = bf2f((ushort)xch[xi]) + bf2f((ushort)xcl[xi]);
        float Bv[6];
        const float* br = sdbc + tt*32 + 8 + p*6;
        if (p == 0){
          const float4 a = *(const float4*)br;
          const float2 b = *(const float2*)(br + 4);
          Bv[0]=a.x; Bv[1]=a.y; Bv[2]=a.z; Bv[3]=a.w; Bv[4]=b.x; Bv[5]=b.y;
        } else {
          const float2 a = *(const float2*)br;
          const float4 b = *(const float4*)(br + 2);
          Bv[0]=a.x; Bv[1]=a.y; Bv[2]=b.x; Bv[3]=b.y; Bv[4]=b.z; Bv[5]=b.w;
        }
        const float dx = dtv * xcv;
        dts += dtv;
        #pragma unroll
        for (int s = 0; s < 6; ++s){
          const float dA = __expf(dtv*Av[s]);
          h[s] = fmaf(dA, h[s], dx*Bv[s]);
        }
      }
    }
    const size_t base = (size_t)bid*SD*NF + n;
    #pragma unroll
    for (int s = 0; s < 6; ++s){
      ap [base + (p*6+s)*NF] = __expf(Av[s]*dts);
      hfb[base + (p*6+s)*NF] = h[s];
    }
  }
}

// ---- K3b: sequential combine across chunks
__global__ __launch_bounds__(128) void k_scan_combine(
    const float* __restrict__ ap, const float* __restrict__ hfb, float* __restrict__ hinit){
  const int sq = blockIdx.x;
  const int n = threadIdx.x;
  float h[SD];
  #pragma unroll
  for (int s = 0; s < SD; ++s) h[s] = 0.f;
  for (int c = 0; c < NCH; ++c){
    const size_t base = ((size_t)sq*NCH + c)*SD*NF + n;
    #pragma unroll
    for (int s = 0; s < SD; ++s){
      hinit[base + s*NF] = h[s];
      h[s] = fmaf(ap[base + s*NF], h[s], hfb[base + s*NF]);
    }
  }
}

// ---- K3c (R8 known-good): scan pass 2 + gate (power-trick dA with fallback)
__global__ __launch_bounds__(128) void k_scan_pass2(
    const float* __restrict__ dtb, const float* __restrict__ xcc,
    const float* __restrict__ Bmb, const float* __restrict__ Cmb,
    const float* __restrict__ alog, const float* __restrict__ hinit,
    const float* __restrict__ zb, const float* __restrict__ Dv,
    float* __restrict__ yb){
  const int bid = blockIdx.x;
  const int sq = bid / NCH, c = bid - sq*NCH;
  const int t0 = c*CLEN;
  const int lim = (TL - t0 < CLEN) ? (TL - t0) : CLEN;
  const int n = threadIdx.x;
  const float4* A4 = (const float4*)(alog + (size_t)n*SD);
  float4 Aa = A4[0], Ab = A4[1], Ac = A4[2];
  float Av[SD] = {Aa.x,Aa.y,Aa.z,Aa.w, Ab.x,Ab.y,Ab.z,Ab.w, Ac.x,Ac.y,Ac.z,Ac.w};
  #pragma unroll
  for (int s = 0; s < SD; ++s) Av[s] = -__expf(Av[s]);
  bool fast = true;
  #pragma unroll
  for (int s = 0; s < SD; ++s)
    fast = fast && (fabsf(Av[s] + (float)(s + 1)) <= 1e-3f);
  const float dvn = Dv[n];
  float h[SD];
  const size_t hbase = (size_t)bid*SD*NF + n;
  #pragma unroll
  for (int s = 0; s < SD; ++s) h[s] = hinit[hbase + s*NF];
  const size_t tok0 = (size_t)sq*TL + t0;
  if (fast){
    for (int tt = 0; tt < lim; ++tt){
      const size_t tok = tok0 + tt;
      float dtv = dtb[tok*NF + n];
      float xcv = xcc[tok*NF + n];
      float dx  = dtv * xcv;
      const float4* B4 = (const float4*)(Bmb + tok*SD);
      const float4* C4 = (const float4*)(Cmb + tok*SD);
      float4 Ba=B4[0], Bb=B4[1], Bc=B4[2];
      float4 Ca=C4[0], Cb=C4[1], Cc=C4[2];
      float Bv[SD] = {Ba.x,Ba.y,Ba.z,Ba.w, Bb.x,Bb.y,Bb.z,Bb.w, Bc.x,Bc.y,Bc.z,Bc.w};
      float Cv[SD] = {Ca.x,Ca.y,Ca.z,Ca.w, Cb.x,Cb.y,Cb.z,Cb.w, Cc.x,Cc.y,Cc.z,Cc.w};
      const float q = __expf(-dtv);
      float dA = q;
      float yv = 0.f;
      h[0] = fmaf(dA, h[0], dx*Bv[0]);
      yv = fmaf(h[0], Cv[0], yv);
      #pragma unroll
      for (int s = 1; s < SD; ++s){
        dA *= q;
        h[s] = fmaf(dA, h[s], dx*Bv[s]);
        yv = fmaf(h[s], Cv[s], yv);
      }
      float zv = zb[tok*NF + n];
      yb[tok*NF + n] = fmaf(dvn, xcv, yv) * siluf(zv);
    }
  } else {
    for (int tt = 0; tt < lim; ++tt){
      const size_t tok = tok0 + tt;
      float dtv = dtb[tok*NF + n];
      float xcv = xcc[tok*NF + n];
      float dx  = dtv * xcv;
      const float4* B4 = (const float4*)(Bmb + tok*SD);
      const float4* C4 = (const float4*)(Cmb + tok*SD);
      float4 Ba=B4[0], Bb=B4[1], Bc=B4[2];
      float4 Ca=C4[0], Cb=C4[1], Cc=C4[2];
      float Bv[SD] = {Ba.x,Ba.y,Ba.z,Ba.w, Bb.x,Bb.y,Bb.z,Bb.w, Bc.x,Bc.y,Bc.z,Bc.w};
      float Cv[SD] = {Ca.x,Ca.y,Ca.z,Ca.w, Cb.x,Cb.y,Cb.z,Cb.w, Cc.x,Cc.y,Cc.z,Cc.w};
      float yv = 0.f;
      #pragma unroll
      for (int s = 0; s < SD; ++s){
        float dA = __expf(dtv*Av[s]);
        h[s] = fmaf(dA, h[s], dx*Bv[s]);
        yv = fmaf(h[s], Cv[s], yv);
      }
      float zv = zb[tok*NF + n];
      yb[tok*NF + n] = fmaf(dvn, xcv, yv) * siluf(zv);
    }
  }
}

// ---- K4 (R8 known-good): seq += yb @ ow^T + ob via MFMA bf16x3.
__global__ __launch_bounds__(256) void k_gate_out(
    const float* __restrict__ yb,
    const ushort* __restrict__ wh, const ushort* __restrict__ wl, const float* __restrict__ ob,
    float* __restrict__ seq){
  __shared__ short xsh[MT*NF];
  __shared__ short xsl[MT*NF];
  const int tid = threadIdx.x;
  const int tok0 = blockIdx.x * MT;

  #pragma unroll
  for (int i = 0; i < 8; ++i){
    const int r  = (tid & 15) + ((i & 3) << 4);
    const int nq = (tid >> 4) + ((i >> 2) << 4);
    const int tok = tok0 + r;
    float4 v = make_float4(0.f,0.f,0.f,0.f);
    if (tok < NTOK) v = *(const float4*)(yb + (size_t)tok*NF + nq*4);
    const ushort h0 = bf16r(v.x), h1 = bf16r(v.y), h2 = bf16r(v.z), h3 = bf16r(v.w);
    const ushort l0 = bf16r(v.x - bf2f(h0)), l1 = bf16r(v.y - bf2f(h1));
    const ushort l2 = bf16r(v.z - bf2f(h2)), l3 = bf16r(v.w - bf2f(h3));
    const int hi = r*NF + ((nq*4) ^ ((r & 7) << 3));
    *(uint2*)&xsh[hi] = make_uint2((uint)h0 | ((uint)h1 << 16), (uint)h2 | ((uint)h3 << 16));
    *(uint2*)&xsl[hi] = make_uint2((uint)l0 | ((uint)l1 << 16), (uint)l2 | ((uint)l3 << 16));
  }
  __syncthreads();

  const int w = tid >> 6, lane = tid & 63;
  const int cl = lane & 15, q8 = (lane >> 4) * 8;
  const int obase = w * 32;
  f32x4 acc[4][2];
  #pragma unroll
  for (int m = 0; m < 4; ++m)
    #pragma unroll
    for (int nt = 0; nt < 2; ++nt) acc[m][nt] = (f32x4){0.f,0.f,0.f,0.f};

  for (int c = 0; c < 4; ++c){
    bf16x8 ah[4], al[4];
    #pragma unroll
    for (int m = 0; m < 4; ++m){
      const int r = m*16 + cl;
      const int hi = r*NF + ((c*32 + q8) ^ ((r & 7) << 3));
      ah[m] = *(const bf16x8*)&xsh[hi];
      al[m] = *(const bf16x8*)&xsl[hi];
    }
    #pragma unroll
    for (int nt = 0; nt < 2; ++nt){
      const int o = obase + nt*16 + cl;
      const size_t wo = (size_t)o*NF + c*32 + q8;
      const bf16x8 bh = *(const bf16x8*)(wh + wo);
      const bf16x8 bl = *(const bf16x8*)(wl + wo);
      #pragma unroll
      for (int m = 0; m < 4; ++m){
        acc[m][nt] = __builtin_amdgcn_mfma_f32_16x16x32_bf16(ah[m], bh, acc[m][nt], 0, 0, 0);
        acc[m][nt] = __builtin_amdgcn_mfma_f32_16x16x32_bf16(al[m], bh, acc[m][nt], 0, 0, 0);
        acc[m][nt] = __builtin_amdgcn_mfma_f32_16x16x32_bf16(ah[m], bl, acc[m][nt], 0, 0, 0);
      }
    }
  }

  const int rbase = (lane >> 4) * 4;
  #pragma unroll
  for (int nt = 0; nt < 2; ++nt){
    const int o = obase + nt*16 + cl;
    const float bias = ob[o];
    #pragma unroll
    for (int m = 0; m < 4; ++m)
      #pragma unroll
      for (int j2 = 0; j2 < 4; ++j2){
        const int tok = tok0 + m*16 + rbase + j2;
        if (tok < NTOK){
          float* dst = seq + (size_t)tok*NF + o;
          *dst = *dst + acc[m][nt][j2] + bias;
        }
      }
  }
}

// ---- K5a (R8 known-good): cross = main @ cb_w^T + cb_b via MFMA bf16x3.
__global__ __launch_bounds__(256) void k_cross_gemm(
    const float* __restrict__ seq,
    const ushort* __restrict__ wh, const ushort* __restrict__ wl, const float* __restrict__ cbb,
    float* __restrict__ cross){
  __shared__ short xsh[MT*NF];
  __shared__ short xsl[MT*NF];
  const int tid = threadIdx.x;
  const int tok0 = blockIdx.x * MT;

  #pragma unroll
  for (int i = 0; i < 8; ++i){
    const int r  = (tid & 15) + ((i & 3) << 4);
    const int nq = (tid >> 4) + ((i >> 2) << 4);
    const int tok = tok0 + r;
    float4 v = make_float4(0.f,0.f,0.f,0.f);
    if (tok < NTOK){
      int b = tok / 30000, rr = tok - b*30000;
      int t = rr / 30, k = rr - t*30;
      v = *(const float4*)(seq + ((size_t)(b*30 + k)*TL + t)*NF + nq*4);
    }
    const ushort h0 = bf16r(v.x), h1 = bf16r(v.y), h2 = bf16r(v.z), h3 = bf16r(v.w);
    const ushort l0 = bf16r(v.x - bf2f(h0)), l1 = bf16r(v.y - bf2f(h1));
    const ushort l2 = bf16r(v.z - bf2f(h2)), l3 = bf16r(v.w - bf2f(h3));
    const int hi = r*NF + ((nq*4) ^ ((r & 7) << 3));
    *(uint2*)&xsh[hi] = make_uint2((uint)h0 | ((uint)h1 << 16), (uint)h2 | ((uint)h3 << 16));
    *(uint2*)&xsl[hi] = make_uint2((uint)l0 | ((uint)l1 << 16), (uint)l2 | ((uint)l3 << 16));
  }
  __syncthreads();

  const int w = tid >> 6, lane = tid & 63;
  const int cl = lane & 15, q8 = (lane >> 4) * 8;
  const int obase = w * 32;
  f32x4 acc[4][2];
  #pragma unroll
  for (int m = 0; m < 4; ++m)
    #pragma unroll
    for (int nt = 0; nt < 2; ++nt) acc[m][nt] = (f32x4){0.f,0.f,0.f,0.f};

  for (int c = 0; c < 4; ++c){
    bf16x8 ah[4], al[4];
    #pragma unroll
    for (int m = 0; m < 4; ++m){
      const int r = m*16 + cl;
      const int hi = r*NF + ((c*32 + q8) ^ ((r & 7) << 3));
      ah[m] = *(const bf16x8*)&xsh[hi];
      al[m] = *(const bf16x8*)&xsl[hi];
    }
    #pragma unroll
    for (int nt = 0; nt < 2; ++nt){
      const int o = obase + nt*16 + cl;
      const size_t wo = (size_t)o*NF + c*32 + q8;
      const bf16x8 bh = *(const bf16x8*)(wh + wo);
      const bf16x8 bl = *(const bf16x8*)(wl + wo);
      #pragma unroll
      for (int m = 0; m < 4; ++m){
        acc[m][nt] = __builtin_amdgcn_mfma_f32_16x16x32_bf16(ah[m], bh, acc[m][nt], 0, 0, 0);
        acc[m][nt] = __builtin_amdgcn_mfma_f32_16x16x32_bf16(al[m], bh, acc[m][nt], 0, 0, 0);
        acc[m][nt] = __builtin_amdgcn_mfma_f32_16x16x32_bf16(ah[m], bl, acc[m][nt], 0, 0, 0);
      }
    }
  }

  const int rbase = (lane >> 4) * 4;
  #pragma unroll
  for (int nt = 0; nt < 2; ++nt){
    const int o = obase + nt*16 + cl;
    const float bias = cbb[o];
    #pragma unroll
    for (int m = 0; m < 4; ++m)
      #pragma unroll
      for (int j2 = 0; j2 < 4; ++j2){
        const int tok = tok0 + m*16 + rbase + j2;
        if (tok < NTOK) cross[(size_t)tok*NF + o] = acc[m][nt][j2] + bias;
      }
  }
}

// ---- K5b: LN1 -> gelu -> +main -> LN2 -> transposed write. 32 tokens/block.
__global__ __launch_bounds__(256) void k_cross_ln(
    const float* __restrict__ seq, const float* __restrict__ cross,
    const float* __restrict__ clnw, const float* __restrict__ clnb,
    const float* __restrict__ flnw, const float* __restrict__ flnb,
    float* __restrict__ out){
  __shared__ float fs[32*LNP];
  const int tid = threadIdx.x;
  const int tok0 = blockIdx.x * 32;
  const int j16 = tid >> 4, l16 = tid & 15;

  for (int it = 0; it < 2; ++it){
    const int jj = j16 + 16*it;
    const int tok = tok0 + jj;
    const int b = tok / 30000, rr = tok - b*30000;
    const int t = rr / 30, k = rr - t*30;
    const float* cp = cross + (size_t)tok*NF;
    const float* mp = seq + ((size_t)(b*30 + k)*TL + t)*NF;
    float cv[8]; float s = 0.f, s2 = 0.f;
    #pragma unroll
    for (int i = 0; i < 8; ++i){
      float f = cp[l16 + 16*i]; cv[i] = f; s += f; s2 += f*f;
    }
    #pragma unroll
    for (int m = 1; m < 16; m <<= 1){ s += __shfl_xor(s, m, 64); s2 += __shfl_xor(s2, m, 64); }
    float mu = s * (1.f/128.f);
    float rs = rsqrtf(s2*(1.f/128.f) - mu*mu + 1e-5f);
    float rv[8]; float rsum = 0.f, rsum2 = 0.f;
    #pragma unroll
    for (int i = 0; i < 8; ++i){
      int n = l16 + 16*i;
      float cn = (cv[i] - mu)*rs*clnw[n] + clnb[n];
      float g = 0.5f*cn*(1.f + erff(cn*0.70710678118f));
      float res = mp[n] + g;
      rv[i] = res; rsum += res; rsum2 += res*res;
    }
    #pragma unroll
    for (int m = 1; m < 16; m <<= 1){ rsum += __shfl_xor(rsum, m, 64); rsum2 += __shfl_xor(rsum2, m, 64); }
    float mu2 = rsum * (1.f/128.f);
    float rs2 = rsqrtf(rsum2*(1.f/128.f) - mu2*mu2 + 1e-5f);
    #pragma unroll
    for (int i = 0; i < 8; ++i){
      int n = l16 + 16*i;
      fs[jj*LNP + n] = (rv[i] - mu2)*rs2*flnw[n] + flnb[n];
    }
  }
  __syncthreads();

  #pragma unroll
  for (int i = 0; i < 16; ++i){
    const int e = tid + i*256;
    const int j = e & 31, n = e >> 5;
    const int tok = tok0 + j;
    const int b = tok / 30000, rr = tok - b*30000;
    out[(size_t)(b*NF + n)*30000 + rr] = fs[j*LNP + n];
  }
}

extern "C" void kernel_launch(void* const* d_in, const int* in_sizes, int n_in,
                              void* d_out, int out_size, void* d_ws, size_t ws_size,
                              hipStream_t stream){
  const float* x       = (const float*)d_in[0];
  const float* ln_w    = (const float*)d_in[1];
  const float* ln_b    = (const float*)d_in[2];
  const float* in_w    = (const float*)d_in[3];
  const float* in_b    = (const float*)d_in[4];
  const float* conv_w  = (const float*)d_in[5];
  const float* conv_b  = (const float*)d_in[6];
  const float* xp_w    = (const float*)d_in[7];
  const float* dtp_w   = (const float*)d_in[8];
  const float* dtp_b   = (const float*)d_in[9];
  const float* A_log   = (const float*)d_in[10];
  const float* Dv      = (const float*)d_in[11];
  const float* out_w   = (const float*)d_in[12];
  const float* out_b   = (const float*)d_in[13];
  const float* cb_w    = (const float*)d_in[14];
  const float* cb_b    = (const float*)d_in[15];
  const float* cb_ln_w = (const float*)d_in[16];
  const float* cb_ln_b = (const float*)d_in[17];
  const float* fin_ln_w= (const float*)d_in[18];
  const float* fin_ln_b= (const float*)d_in[19];
  float* out = (float*)d_out;

  const size_t SEQSZ = (size_t)BKS*TL*NF;        // 7,680,000 floats
  const size_t CHSZ  = (size_t)BKS*NF*NCH*SD;    // 2,949,120 floats
  const size_t FBASE = 6*SEQSZ + 2*(size_t)BKS*TL*SD;   // fp32 region
  const size_t BASE  = FBASE + WCNT;                    // + bf16 pool (2*WCNT ushorts)
  float* ws  = (float*)d_ws;
  float* seq = ws;
  float* xcr = ws + SEQSZ;
  float* zb  = ws + 2*SEQSZ;
  float* xcc = ws + 3*SEQSZ;
  float* dtb = ws + 4*SEQSZ;
  float* yb  = ws + 5*SEQSZ;
  float* Bmb = ws + 6*SEQSZ;
  float* Cmb = Bmb + (size_t)BKS*TL*SD;
  ushort* wbh = (ushort*)(ws + FBASE);
  ushort* wbl = wbh + WCNT;
  if (ws_size < BASE*sizeof(float)) return;

  // Liveness aliasing: ap/hfb -> yb region; hinit -> xcr; cross -> dtb.
  float* ap    = yb;
  float* hfb   = yb + CHSZ;
  float* hinit = xcr;
  float* cross = dtb;

  k_wconv<<<(WCNT + 255)/256, 256, 0, stream>>>(in_w, out_w, cb_w, xp_w, wbh, wbl);
  k_ingest<<<2*TL, 256, 0, stream>>>(x, seq);
  for (int l = 0; l < 4; ++l){
    k_ln_inproj<<<NBLK, 256, 0, stream>>>(seq, ln_w + l*NF, ln_b + l*NF,
        wbh + (size_t)l*32768, wbl + (size_t)l*32768, in_b + l*2*NF, xcr, zb);
    k_conv_scan1<<<BKS*NCH, 256, 0, stream>>>(xcr, conv_w + (size_t)l*NF*4, conv_b + l*NF,
        wbh + OFF_XW + (size_t)l*4096, wbl + OFF_XW + (size_t)l*4096,
        dtp_w + (size_t)l*NF*RD, dtp_b + l*NF,
        A_log + (size_t)l*NF*SD, xcc, dtb, Bmb, Cmb, ap, hfb);
    k_scan_combine<<<BKS, NF, 0, stream>>>(ap, hfb, hinit);
    k_scan_pass2<<<BKS*NCH, NF, 0, stream>>>(dtb, xcc, Bmb, Cmb, A_log + (size_t)l*NF*SD,
        hinit, zb, Dv + l*NF, yb);
    k_gate_out<<<NBLK, 256, 0, stream>>>(yb,
        wbh + OFF_OW + (size_t)l*16384, wbl + OFF_OW + (size_t)l*16384, out_b + l*NF, seq);
  }
  k_cross_gemm<<<NBLK, 256, 0, stream>>>(seq, wbh + OFF_CBW, wbl + OFF_CBW, cb_b, cross);
  k_cross_ln<<<NTOK/32, 256, 0, stream>>>(seq, cross, cb_ln_w, cb_ln_b, fin_ln_w, fin_ln_b, out);
}